// Round 6
// baseline (811.222 us; speedup 1.0000x reference)
//
#include <hip/hip_runtime.h>
#include <cstdint>
#include <cstddef>

#define T_TOK 8192
#define D_DIM 1024
#define F_DIM 4096
#define E_NUM 8
#define CAP   2560
#define BKS   32
#define MYB   20            // CAP / 128
#define NWRK  (E_NUM * MYB) // 160 compacted work slots
#define LDSB  16384         // bytes per pipeline buffer (A 8KB + B 8KB)

typedef __attribute__((ext_vector_type(8))) short bf16x8;
typedef __attribute__((ext_vector_type(8))) unsigned short u16x8;
typedef __attribute__((ext_vector_type(4))) float f32x4;

typedef const __attribute__((address_space(1))) void* gas_ptr;
typedef __attribute__((address_space(3))) void* las_ptr;

__device__ __forceinline__ unsigned short f2bf(float f) {
  unsigned u = __float_as_uint(f);
  u += 0x7FFF + ((u >> 16) & 1);
  return (unsigned short)(u >> 16);
}

__device__ __forceinline__ float gelu_f(float x) {
  float u = 0.7978845608028654f * (x + 0.044715f * x * x * x);
  float t = 1.0f - 2.0f / (__expf(2.0f * u) + 1.0f);   // tanh(u)
  return 0.5f * x * (1.0f + t);
}

// XCD-chunked bijective swizzle (nwg % 8 == 0 for all our launches).
__device__ __forceinline__ int xcd_swizzle(int bid, int nwg) {
  int q = nwg >> 3;
  return (bid & 7) * q + (bid >> 3);
}

// counted-vmcnt pipeline barrier: never drains to 0 in steady state
#define PIPE_BAR4() asm volatile("s_waitcnt vmcnt(4)\n\ts_barrier" ::: "memory")
#define PIPE_BAR0() asm volatile("s_waitcnt vmcnt(0)\n\ts_barrier" ::: "memory")

// ---------------- routing: logits (fp32), top-2, gates; also emit bf16 x ----
__global__ __launch_bounds__(256) void route_kernel(
    const float* __restrict__ x, const float* __restrict__ wr,
    unsigned short* __restrict__ xbf, int2* __restrict__ tokE,
    float2* __restrict__ tokG)
{
  int tid = threadIdx.x;
  int l = tid & 63;
  int w = tid >> 6;
  int t = blockIdx.x * 4 + w;
  const float4* xr = (const float4*)(x + (size_t)t * D_DIM);
  ushort4* xbr = (ushort4*)(xbf + (size_t)t * D_DIM);
  float acc[E_NUM];
#pragma unroll
  for (int e = 0; e < E_NUM; ++e) acc[e] = 0.f;
#pragma unroll
  for (int c = 0; c < D_DIM / 256; ++c) {
    float4 xv = xr[c * 64 + l];
    ushort4 bv;
    bv.x = f2bf(xv.x); bv.y = f2bf(xv.y); bv.z = f2bf(xv.z); bv.w = f2bf(xv.w);
    xbr[c * 64 + l] = bv;
#pragma unroll
    for (int e = 0; e < E_NUM; ++e) {
      float4 wv = ((const float4*)(wr + (size_t)e * D_DIM))[c * 64 + l];
      acc[e] += xv.x * wv.x + xv.y * wv.y + xv.z * wv.z + xv.w * wv.w;
    }
  }
#pragma unroll
  for (int e = 0; e < E_NUM; ++e) {
#pragma unroll
    for (int s = 32; s > 0; s >>= 1) acc[e] += __shfl_xor(acc[e], s);
  }
  if (l == 0) {
    int e1 = 0; float v1 = acc[0];
#pragma unroll
    for (int e = 1; e < E_NUM; ++e) if (acc[e] > v1) { v1 = acc[e]; e1 = e; }
    int e2 = -1; float v2 = -3.4e38f;
#pragma unroll
    for (int e = 0; e < E_NUM; ++e) if (e != e1 && acc[e] > v2) { v2 = acc[e]; e2 = e; }
    float s = __expf(v2 - v1);
    float g1 = 1.f / (1.f + s);
    tokE[t] = make_int2(e1, e2);
    tokG[t] = make_float2(g1, s * g1);
  }
}

// ---------------- capacity scan: token-order cumsum per expert --------------
__global__ __launch_bounds__(256) void scan_kernel(
    const int2* __restrict__ tokE, const float2* __restrict__ tokG,
    int* __restrict__ dispatch, float* __restrict__ sgate, int* __restrict__ cnt)
{
  int e = blockIdx.x;
  int tid = threadIdx.x;
  int l = tid & 63;
  int w = tid >> 6;
  __shared__ int wsum[4];
  int base = 0;
  for (int chunk = 0; chunk < T_TOK; chunk += 256) {
    int t = chunk + tid;
    int2 te = tokE[t];
    float2 tg = tokG[t];
    bool f1 = (te.x == e);
    bool f2 = (te.y == e);
    bool f = f1 || f2;
    unsigned long long m = __ballot(f);
    int rank = __popcll(m & ((1ull << l) - 1ull));
    if (l == 0) wsum[w] = __popcll(m);
    __syncthreads();
    int woff = 0;
#pragma unroll
    for (int i = 0; i < 4; ++i) if (i < w) woff += wsum[i];
    int tot = wsum[0] + wsum[1] + wsum[2] + wsum[3];
    int pos = base + woff + rank;
    if (f && pos < CAP) {
      dispatch[e * CAP + pos] = t;
      sgate[e * CAP + pos] = f1 ? tg.x : tg.y;
    }
    base += tot;
    __syncthreads();
  }
  int start = base < CAP ? base : CAP;
  for (int p = start + tid; p < CAP; p += 256) {
    dispatch[e * CAP + p] = T_TOK;
    sgate[e * CAP + p] = 0.f;
  }
  if (tid == 0) cnt[e] = base < CAP ? base : CAP;
}

// ---------------- plan: compact (expert, m0) work list ----------------------
__global__ __launch_bounds__(64) void plan_kernel(
    const int* __restrict__ cnt, int* __restrict__ blkE, int* __restrict__ blkM)
{
  __shared__ int pre[E_NUM + 1];
  if (threadIdx.x == 0) {
    int s = 0;
    for (int e = 0; e < E_NUM; ++e) { pre[e] = s; s += (cnt[e] + 127) >> 7; }
    pre[E_NUM] = s;
  }
  __syncthreads();
  for (int w = threadIdx.x; w < NWRK; w += 64) {
    if (w < pre[E_NUM]) {
      int e = 0;
#pragma unroll
      for (int i = 1; i < E_NUM; ++i) if (w >= pre[i]) e = i;
      blkE[w] = e;
      blkM[w] = (w - pre[e]) << 7;
    } else {
      blkE[w] = -1;
      blkM[w] = 0;
    }
  }
}

// ---------------- transpose + fp32->bf16: (K,N) -> (N,K), 64x64 tiles -------
__global__ __launch_bounds__(256) void transpose_kernel(
    const float* __restrict__ src, unsigned short* __restrict__ dst,
    int K, int N)
{
  const float* s = src + (size_t)blockIdx.z * K * N;
  unsigned short* d = dst + (size_t)blockIdx.z * K * N;
  __shared__ float tile[64][65];
  int n0 = blockIdx.x * 64;
  int k0 = blockIdx.y * 64;
  int tid = threadIdx.x;
  int r = tid >> 4;           // 0..15
  int c4 = (tid & 15) * 4;
#pragma unroll
  for (int i = 0; i < 4; ++i) {
    int row = r + i * 16;
    float4 v = *(const float4*)&s[(size_t)(k0 + row) * N + n0 + c4];
    tile[row][c4] = v.x; tile[row][c4 + 1] = v.y;
    tile[row][c4 + 2] = v.z; tile[row][c4 + 3] = v.w;
  }
  __syncthreads();
  int n = tid >> 2;           // 0..63
  int kg = tid & 3;
#pragma unroll
  for (int j = 0; j < 2; ++j) {
    int kc = kg * 2 + j;      // 0..7
    u16x8 o;
#pragma unroll
    for (int q = 0; q < 8; ++q) o[q] = f2bf(tile[kc * 8 + q][n]);
    *(u16x8*)&d[(size_t)(n0 + n) * K + k0 + kc * 8] = o;
  }
}

// LDS swizzle: tile unit u = row*4 + s (16B units, 32 bf16 per row)
// stored at u' = u ^ ((u>>3)&7); involution (key from XOR-invariant bits).
// Read (row, s=lhi): 16 lanes/lhi-group spread over all 8 16B-columns -> 2-way (free).

// ---------------- GEMM1: h = gelu(xg @ w1 + b1), h stored bf16 --------------
#define G1_NXB (F_DIM / 128)   // 32
__global__ __launch_bounds__(256, 3) void gemm1_kernel(
    const unsigned short* __restrict__ xbf,   // (T+1, D) bf16, row T zeroed
    const unsigned short* __restrict__ w1t,   // (F, D) bf16 per expert
    const float* __restrict__ b1,             // (E, F)
    const int* __restrict__ dispatch,         // (E, CAP)
    const int* __restrict__ cnt,              // (E)
    const int* __restrict__ blkE,             // (NWRK) compacted expert id
    const int* __restrict__ blkM,             // (NWRK) compacted m0
    unsigned short* __restrict__ h,           // (CAP, F) bf16 per expert
    int eSel, size_t w1stride, size_t hstride)
{
  int wg = xcd_swizzle(blockIdx.x, gridDim.x);
  int e, m0, nx, ez;
  if (eSel >= 0) {            // tier B: single expert, buffers not strided
    int my = wg % MYB; nx = wg / MYB;
    e = eSel; ez = 0; m0 = my * 128;
    if (m0 >= cnt[e]) return;
  } else {                    // tier A: balanced compacted work list
    int w = wg % NWRK; nx = wg / NWRK;
    e = blkE[w]; if (e < 0) return;
    ez = e; m0 = blkM[w];
  }
  const unsigned short* w1e = w1t + (size_t)ez * w1stride;
  unsigned short* he = h + (size_t)ez * hstride;
  int n0 = nx * 128;
  int tid = threadIdx.x;
  int l = tid & 63;
  int wid = tid >> 6;
  int wm = wid >> 1, wn = wid & 1;
  int lrow = l & 15, lhi = l >> 4;

  __shared__ __align__(16) char lds[3 * LDSB];

  // stage slots (per thread: 2 A-units + 2 B-units, 16B each)
  const unsigned short* ag[2];
  const unsigned short* bg[2];
  int ldsA[2], ldsB[2];
#pragma unroll
  for (int j = 0; j < 2; ++j) {
    int chunk = wid * 2 + j;            // 0..7 (wave-uniform)
    int U = chunk * 64 + l;             // linear LDS unit this lane writes
    int u = U ^ ((U >> 3) & 7);         // inverse swizzle -> tile coords
    int row = u >> 2, s = u & 3;
    int tok = dispatch[e * CAP + m0 + row];
    ag[j] = xbf + (size_t)tok * D_DIM + s * 8;
    bg[j] = w1e + (size_t)(n0 + row) * D_DIM + s * 8;
    ldsA[j] = chunk * 1024;
    ldsB[j] = 8192 + chunk * 1024;
  }

  // swizzled read offsets (bytes within buffer)
  int aoff[4], boff[4];
#pragma unroll
  for (int m = 0; m < 4; ++m) {
    int row = wm * 64 + m * 16 + lrow;
    int u = row * 4 + lhi;
    aoff[m] = (u ^ ((row >> 1) & 7)) * 16;
    int colr = wn * 64 + m * 16 + lrow;
    int ub = colr * 4 + lhi;
    boff[m] = 8192 + (ub ^ ((colr >> 1) & 7)) * 16;
  }

  f32x4 acc[4][4];
#pragma unroll
  for (int m = 0; m < 4; ++m)
#pragma unroll
    for (int n = 0; n < 4; ++n) acc[m][n] = (f32x4){0.f, 0.f, 0.f, 0.f};

#define STAGE1(BASE, KOFF) do { \
    __builtin_amdgcn_global_load_lds((gas_ptr)(ag[0] + (KOFF)), (las_ptr)(lds + (BASE) + ldsA[0]), 16, 0, 0); \
    __builtin_amdgcn_global_load_lds((gas_ptr)(bg[0] + (KOFF)), (las_ptr)(lds + (BASE) + ldsB[0]), 16, 0, 0); \
    __builtin_amdgcn_global_load_lds((gas_ptr)(ag[1] + (KOFF)), (las_ptr)(lds + (BASE) + ldsA[1]), 16, 0, 0); \
    __builtin_amdgcn_global_load_lds((gas_ptr)(bg[1] + (KOFF)), (las_ptr)(lds + (BASE) + ldsB[1]), 16, 0, 0); \
  } while (0)

  const int NT = D_DIM / BKS;   // 32
  STAGE1(0, 0);
  STAGE1(LDSB, BKS);
  PIPE_BAR4();                  // buf0 globally ready; buf1 (4 loads) in flight

  int cb = 0, sb = 2 * LDSB, koff = 2 * BKS;
  for (int t = 0; t < NT; ++t) {
    if (t + 2 < NT) { STAGE1(sb, koff); koff += BKS; }
    bf16x8 af[4], bfr[4];
#pragma unroll
    for (int m = 0; m < 4; ++m) af[m] = *(const bf16x8*)(lds + cb + aoff[m]);
#pragma unroll
    for (int n = 0; n < 4; ++n) bfr[n] = *(const bf16x8*)(lds + cb + boff[n]);
    __builtin_amdgcn_s_setprio(1);
#pragma unroll
    for (int m = 0; m < 4; ++m)
#pragma unroll
      for (int n = 0; n < 4; ++n)
        acc[m][n] = __builtin_amdgcn_mfma_f32_16x16x32_bf16(af[m], bfr[n], acc[m][n], 0, 0, 0);
    __builtin_amdgcn_s_setprio(0);
    if (t + 1 < NT) {
      if (t + 2 < NT) PIPE_BAR4(); else PIPE_BAR0();
      cb = (cb == 2 * LDSB) ? 0 : cb + LDSB;
      sb = (sb == 2 * LDSB) ? 0 : sb + LDSB;
    }
  }

  int colg[4]; float b1v[4];
#pragma unroll
  for (int n = 0; n < 4; ++n) {
    colg[n] = n0 + wn * 64 + n * 16 + lrow;
    b1v[n] = b1[e * F_DIM + colg[n]];
  }
#pragma unroll
  for (int m = 0; m < 4; ++m) {
    int rb = m0 + wm * 64 + m * 16 + lhi * 4;
#pragma unroll
    for (int j = 0; j < 4; ++j) {
      int r = rb + j;
      unsigned short* hr = he + (size_t)r * F_DIM;
#pragma unroll
      for (int n = 0; n < 4; ++n) {
        float v = acc[m][n][j] + b1v[n];
        hr[colg[n]] = f2bf(gelu_f(v));
      }
    }
  }
}

// ---------------- GEMM2: y = h @ w2 + b2; out[tok] += gate*y (atomic) -------
#define G2_NXB (D_DIM / 128)   // 8
__global__ __launch_bounds__(256, 3) void gemm2_kernel(
    const unsigned short* __restrict__ h,     // (CAP, F) bf16 per expert
    const unsigned short* __restrict__ w2t,   // (D, F) bf16 per expert
    const float* __restrict__ b2,             // (E, D)
    const int* __restrict__ dispatch,
    const float* __restrict__ sgate,
    const int* __restrict__ cnt,
    const int* __restrict__ blkE,
    const int* __restrict__ blkM,
    float* __restrict__ out,                  // (T, D) fp32, zero-initialized
    int eSel, size_t w2stride, size_t hstride)
{
  int wg = xcd_swizzle(blockIdx.x, gridDim.x);
  int e, m0, nx, ez;
  if (eSel >= 0) {
    int my = wg % MYB; nx = wg / MYB;
    e = eSel; ez = 0; m0 = my * 128;
    if (m0 >= cnt[e]) return;
  } else {
    int w = wg % NWRK; nx = wg / NWRK;
    e = blkE[w]; if (e < 0) return;
    ez = e; m0 = blkM[w];
  }
  const unsigned short* he = h + (size_t)ez * hstride;
  const unsigned short* w2e = w2t + (size_t)ez * w2stride;
  int n0 = nx * 128;
  int tid = threadIdx.x;
  int l = tid & 63;
  int wid = tid >> 6;
  int wm = wid >> 1, wn = wid & 1;
  int lrow = l & 15, lhi = l >> 4;

  __shared__ __align__(16) char lds[3 * LDSB];

  const unsigned short* ag[2];
  const unsigned short* bg[2];
  int ldsA[2], ldsB[2];
#pragma unroll
  for (int j = 0; j < 2; ++j) {
    int chunk = wid * 2 + j;
    int U = chunk * 64 + l;
    int u = U ^ ((U >> 3) & 7);
    int row = u >> 2, s = u & 3;
    ag[j] = he + (size_t)(m0 + row) * F_DIM + s * 8;
    bg[j] = w2e + (size_t)(n0 + row) * F_DIM + s * 8;
    ldsA[j] = chunk * 1024;
    ldsB[j] = 8192 + chunk * 1024;
  }

  int aoff[4], boff[4];
#pragma unroll
  for (int m = 0; m < 4; ++m) {
    int row = wm * 64 + m * 16 + lrow;
    int u = row * 4 + lhi;
    aoff[m] = (u ^ ((row >> 1) & 7)) * 16;
    int colr = wn * 64 + m * 16 + lrow;
    int ub = colr * 4 + lhi;
    boff[m] = 8192 + (ub ^ ((colr >> 1) & 7)) * 16;
  }

  f32x4 acc[4][4];
#pragma unroll
  for (int m = 0; m < 4; ++m)
#pragma unroll
    for (int n = 0; n < 4; ++n) acc[m][n] = (f32x4){0.f, 0.f, 0.f, 0.f};

#define STAGE2(BASE, KOFF) do { \
    __builtin_amdgcn_global_load_lds((gas_ptr)(ag[0] + (KOFF)), (las_ptr)(lds + (BASE) + ldsA[0]), 16, 0, 0); \
    __builtin_amdgcn_global_load_lds((gas_ptr)(bg[0] + (KOFF)), (las_ptr)(lds + (BASE) + ldsB[0]), 16, 0, 0); \
    __builtin_amdgcn_global_load_lds((gas_ptr)(ag[1] + (KOFF)), (las_ptr)(lds + (BASE) + ldsA[1]), 16, 0, 0); \
    __builtin_amdgcn_global_load_lds((gas_ptr)(bg[1] + (KOFF)), (las_ptr)(lds + (BASE) + ldsB[1]), 16, 0, 0); \
  } while (0)

  const int NT = F_DIM / BKS;   // 128
  STAGE2(0, 0);
  STAGE2(LDSB, BKS);
  PIPE_BAR4();

  int cb = 0, sb = 2 * LDSB, koff = 2 * BKS;
  for (int t = 0; t < NT; ++t) {
    if (t + 2 < NT) { STAGE2(sb, koff); koff += BKS; }
    bf16x8 af[4], bfr[4];
#pragma unroll
    for (int m = 0; m < 4; ++m) af[m] = *(const bf16x8*)(lds + cb + aoff[m]);
#pragma unroll
    for (int n = 0; n < 4; ++n) bfr[n] = *(const bf16x8*)(lds + cb + boff[n]);
    __builtin_amdgcn_s_setprio(1);
#pragma unroll
    for (int m = 0; m < 4; ++m)
#pragma unroll
      for (int n = 0; n < 4; ++n)
        acc[m][n] = __builtin_amdgcn_mfma_f32_16x16x32_bf16(af[m], bfr[n], acc[m][n], 0, 0, 0);
    __builtin_amdgcn_s_setprio(0);
    if (t + 1 < NT) {
      if (t + 2 < NT) PIPE_BAR4(); else PIPE_BAR0();
      cb = (cb == 2 * LDSB) ? 0 : cb + LDSB;
      sb = (sb == 2 * LDSB) ? 0 : sb + LDSB;
    }
  }

  int colg[4]; float b2v[4];
#pragma unroll
  for (int n = 0; n < 4; ++n) {
    colg[n] = n0 + wn * 64 + n * 16 + lrow;
    b2v[n] = b2[e * D_DIM + colg[n]];
  }
#pragma unroll
  for (int m = 0; m < 4; ++m) {
    int rb = m0 + wm * 64 + m * 16 + lhi * 4;
#pragma unroll
    for (int j = 0; j < 4; ++j) {
      int r = rb + j;
      int tok = dispatch[e * CAP + r];
      if (tok < T_TOK) {
        float g = sgate[e * CAP + r];
        float* orow = out + (size_t)tok * D_DIM;
#pragma unroll
        for (int n = 0; n < 4; ++n)
          atomicAdd(&orow[colg[n]], g * (acc[m][n][j] + b2v[n]));
      }
    }
  }
}

// ---------------- host-side launch ------------------------------------------
extern "C" void kernel_launch(void* const* d_in, const int* in_sizes, int n_in,
                              void* d_out, int out_size, void* d_ws, size_t ws_size,
                              hipStream_t stream) {
  const float* x  = (const float*)d_in[0];
  const float* wr = (const float*)d_in[1];
  const float* w1 = (const float*)d_in[2];
  const float* b1 = (const float*)d_in[3];
  const float* w2 = (const float*)d_in[4];
  const float* b2 = (const float*)d_in[5];
  float* out = (float*)d_out;

  char* ws = (char*)d_ws;
  size_t off = 0;
  auto alloc = [&](size_t bytes) -> void* {
    off = (off + 255) & ~(size_t)255;
    void* p = ws + off;
    off += bytes;
    return p;
  };
  int*   dispatch = (int*)alloc((size_t)E_NUM * CAP * 4);
  float* sgate    = (float*)alloc((size_t)E_NUM * CAP * 4);
  int*   cnt      = (int*)alloc((size_t)E_NUM * 4);
  int*   blkE     = (int*)alloc((size_t)NWRK * 4);
  int*   blkM     = (int*)alloc((size_t)NWRK * 4);
  int2*  tokE     = (int2*)alloc((size_t)T_TOK * 8);
  float2* tokG    = (float2*)alloc((size_t)T_TOK * 8);
  unsigned short* xbf = (unsigned short*)alloc((size_t)(T_TOK + 1) * D_DIM * 2);

  const size_t wsz = (size_t)D_DIM * F_DIM * 2;  // one expert weight, bf16 bytes
  const size_t hsz = (size_t)CAP * F_DIM * 2;    // one expert h, bf16 bytes
  size_t remain = ws_size > off ? ws_size - off : 0;
  bool tierA = remain >= (size_t)E_NUM * (2 * wsz + hsz) + (size_t)(1 << 16);

  hipMemsetAsync(out, 0, (size_t)T_TOK * D_DIM * 4, stream);
  hipMemsetAsync(xbf + (size_t)T_TOK * D_DIM, 0, D_DIM * 2, stream);
  route_kernel<<<T_TOK / 4, 256, 0, stream>>>(x, wr, xbf, tokE, tokG);
  scan_kernel<<<E_NUM, 256, 0, stream>>>(tokE, tokG, dispatch, sgate, cnt);
  plan_kernel<<<1, 64, 0, stream>>>(cnt, blkE, blkM);

  if (tierA) {
    unsigned short* w1t = (unsigned short*)alloc((size_t)E_NUM * wsz);
    unsigned short* w2t = (unsigned short*)alloc((size_t)E_NUM * wsz);
    unsigned short* hb  = (unsigned short*)alloc((size_t)E_NUM * hsz);
    transpose_kernel<<<dim3(F_DIM / 64, D_DIM / 64, E_NUM), 256, 0, stream>>>(w1, w1t, D_DIM, F_DIM);
    transpose_kernel<<<dim3(D_DIM / 64, F_DIM / 64, E_NUM), 256, 0, stream>>>(w2, w2t, F_DIM, D_DIM);
    gemm1_kernel<<<dim3(G1_NXB * NWRK), 256, 0, stream>>>(
        xbf, w1t, b1, dispatch, cnt, blkE, blkM, hb, -1, wsz / 2, hsz / 2);
    gemm2_kernel<<<dim3(G2_NXB * NWRK), 256, 0, stream>>>(
        hb, w2t, b2, dispatch, sgate, cnt, blkE, blkM, out, -1, wsz / 2, hsz / 2);
  } else {
    unsigned short* w1t = (unsigned short*)alloc(wsz);
    unsigned short* w2t = (unsigned short*)alloc(wsz);
    unsigned short* hb  = (unsigned short*)alloc(hsz);
    for (int e = 0; e < E_NUM; ++e) {
      transpose_kernel<<<dim3(F_DIM / 64, D_DIM / 64, 1), 256, 0, stream>>>(
          w1 + (size_t)e * D_DIM * F_DIM, w1t, D_DIM, F_DIM);
      gemm1_kernel<<<dim3(G1_NXB * MYB), 256, 0, stream>>>(
          xbf, w1t, b1, dispatch, cnt, blkE, blkM, hb, e, 0, 0);
      transpose_kernel<<<dim3(D_DIM / 64, F_DIM / 64, 1), 256, 0, stream>>>(
          w2 + (size_t)e * D_DIM * F_DIM, w2t, F_DIM, D_DIM);
      gemm2_kernel<<<dim3(G2_NXB * MYB), 256, 0, stream>>>(
          hb, w2t, b2, dispatch, sgate, cnt, blkE, blkM, out, e, 0, 0);
    }
  }
}

// Round 10
// 806.697 us; speedup vs baseline: 1.0056x; 1.0056x over previous
//
#include <hip/hip_runtime.h>
#include <cstdint>
#include <cstddef>

#define T_TOK 8192
#define D_DIM 1024
#define F_DIM 4096
#define E_NUM 8
#define CAP   2560
#define NWMAX 80            // CAP/256 * E_NUM
#define NXB1  (F_DIM / 128) // 32 n-panels for gemm1
#define NXB2  (D_DIM / 128) // 8 n-panels for gemm2
#define BUFB  49152         // bytes per pipeline buffer: A 32KB + B 16KB

typedef __attribute__((ext_vector_type(8))) short bf16x8;
typedef __attribute__((ext_vector_type(8))) unsigned short u16x8;
typedef __attribute__((ext_vector_type(4))) float f32x4;

typedef const __attribute__((address_space(1))) void* gas_ptr;
typedef __attribute__((address_space(3))) void* las_ptr;

__device__ __forceinline__ unsigned short f2bf(float f) {
  unsigned u = __float_as_uint(f);
  u += 0x7FFF + ((u >> 16) & 1);
  return (unsigned short)(u >> 16);
}

__device__ __forceinline__ float gelu_f(float x) {
  float u = 0.7978845608028654f * (x + 0.044715f * x * x * x);
  float t = 1.0f - 2.0f / (__expf(2.0f * u) + 1.0f);   // tanh(u)
  return 0.5f * x * (1.0f + t);
}

// ---------------- routing ---------------------------------------------------
__global__ __launch_bounds__(256) void route_kernel(
    const float* __restrict__ x, const float* __restrict__ wr,
    unsigned short* __restrict__ xbf, int2* __restrict__ tokE,
    float2* __restrict__ tokG)
{
  int tid = threadIdx.x;
  int l = tid & 63;
  int w = tid >> 6;
  int t = blockIdx.x * 4 + w;
  const float4* xr = (const float4*)(x + (size_t)t * D_DIM);
  ushort4* xbr = (ushort4*)(xbf + (size_t)t * D_DIM);
  float acc[E_NUM];
#pragma unroll
  for (int e = 0; e < E_NUM; ++e) acc[e] = 0.f;
#pragma unroll
  for (int c = 0; c < D_DIM / 256; ++c) {
    float4 xv = xr[c * 64 + l];
    ushort4 bv;
    bv.x = f2bf(xv.x); bv.y = f2bf(xv.y); bv.z = f2bf(xv.z); bv.w = f2bf(xv.w);
    xbr[c * 64 + l] = bv;
#pragma unroll
    for (int e = 0; e < E_NUM; ++e) {
      float4 wv = ((const float4*)(wr + (size_t)e * D_DIM))[c * 64 + l];
      acc[e] += xv.x * wv.x + xv.y * wv.y + xv.z * wv.z + xv.w * wv.w;
    }
  }
#pragma unroll
  for (int e = 0; e < E_NUM; ++e) {
#pragma unroll
    for (int s = 32; s > 0; s >>= 1) acc[e] += __shfl_xor(acc[e], s);
  }
  if (l == 0) {
    int e1 = 0; float v1 = acc[0];
#pragma unroll
    for (int e = 1; e < E_NUM; ++e) if (acc[e] > v1) { v1 = acc[e]; e1 = e; }
    int e2 = -1; float v2 = -3.4e38f;
#pragma unroll
    for (int e = 0; e < E_NUM; ++e) if (e != e1 && acc[e] > v2) { v2 = acc[e]; e2 = e; }
    float s = __expf(v2 - v1);
    float g1 = 1.f / (1.f + s);
    tokE[t] = make_int2(e1, e2);
    tokG[t] = make_float2(g1, s * g1);
  }
}

// ---------------- capacity scan ---------------------------------------------
__global__ __launch_bounds__(256) void scan_kernel(
    const int2* __restrict__ tokE, const float2* __restrict__ tokG,
    int* __restrict__ dispatch, float* __restrict__ sgate, int* __restrict__ cnt)
{
  int e = blockIdx.x;
  int tid = threadIdx.x;
  int l = tid & 63;
  int w = tid >> 6;
  __shared__ int wsum[4];
  int base = 0;
  for (int chunk = 0; chunk < T_TOK; chunk += 256) {
    int t = chunk + tid;
    int2 te = tokE[t];
    float2 tg = tokG[t];
    bool f1 = (te.x == e);
    bool f2 = (te.y == e);
    bool f = f1 || f2;
    unsigned long long m = __ballot(f);
    int rank = __popcll(m & ((1ull << l) - 1ull));
    if (l == 0) wsum[w] = __popcll(m);
    __syncthreads();
    int woff = 0;
#pragma unroll
    for (int i = 0; i < 4; ++i) if (i < w) woff += wsum[i];
    int tot = wsum[0] + wsum[1] + wsum[2] + wsum[3];
    int pos = base + woff + rank;
    if (f && pos < CAP) {
      dispatch[e * CAP + pos] = t;
      sgate[e * CAP + pos] = f1 ? tg.x : tg.y;
    }
    base += tot;
    __syncthreads();
  }
  int start = base < CAP ? base : CAP;
  for (int p = start + tid; p < CAP; p += 256) {
    dispatch[e * CAP + p] = T_TOK;
    sgate[e * CAP + p] = 0.f;
  }
  if (tid == 0) cnt[e] = base < CAP ? base : CAP;
}

// ---------------- plan: prefix of 256-row block counts ----------------------
__global__ __launch_bounds__(64) void plan_kernel(
    const int* __restrict__ cnt, int* __restrict__ pre)
{
  if (threadIdx.x == 0) {
    int s = 0;
    for (int e = 0; e < E_NUM; ++e) { pre[e] = s; s += (cnt[e] + 255) >> 8; }
    pre[E_NUM] = s;
  }
}

// ---------------- transpose + fp32->bf16: (K,N) -> (N,K), 64x64 tiles -------
__global__ __launch_bounds__(256) void transpose_kernel(
    const float* __restrict__ src, unsigned short* __restrict__ dst,
    int K, int N)
{
  const float* s = src + (size_t)blockIdx.z * K * N;
  unsigned short* d = dst + (size_t)blockIdx.z * K * N;
  __shared__ float tile[64][65];
  int n0 = blockIdx.x * 64;
  int k0 = blockIdx.y * 64;
  int tid = threadIdx.x;
  int r = tid >> 4;
  int c4 = (tid & 15) * 4;
#pragma unroll
  for (int i = 0; i < 4; ++i) {
    int row = r + i * 16;
    float4 v = *(const float4*)&s[(size_t)(k0 + row) * N + n0 + c4];
    tile[row][c4] = v.x; tile[row][c4 + 1] = v.y;
    tile[row][c4 + 2] = v.z; tile[row][c4 + 3] = v.w;
  }
  __syncthreads();
  int n = tid >> 2;
  int kg = tid & 3;
#pragma unroll
  for (int j = 0; j < 2; ++j) {
    int kc = kg * 2 + j;
    u16x8 o;
#pragma unroll
    for (int q = 0; q < 8; ++q) o[q] = f2bf(tile[kc * 8 + q][n]);
    *(u16x8*)&d[(size_t)(n0 + n) * K + k0 + kc * 8] = o;
  }
}

// ============================================================================
// 8-wave phase-interleaved GEMM: BM=256, BN=128, BK=64, 3 LDS buffers.
// LDS buffer: A[256][64] bf16 (32KB, swizzled) + B[128][64] bf16 (16KB).
// Swizzle: 16B slot s' = s ^ (row & 7) within each row (8 slots/row).
// Pipeline: stage tile t+2 during tile t; end-of-tile s_waitcnt vmcnt(6)
// guarantees (FIFO, 6 newest allowed) tile t+1's 6 loads have landed.
// ============================================================================

// map block -> (e, m0, nx) with runtime-bijective XCD chunking over real work
__device__ __forceinline__ bool map_block(
    const int* __restrict__ pre, int nxb, int eSel,
    int& e, int& m0, int& nx)
{
  int W;
  if (eSel >= 0) W = (pre[eSel + 1] - pre[eSel]) * nxb;
  else W = pre[E_NUM] * nxb;
  int W8 = (W + 7) & ~7;
  if ((int)blockIdx.x >= W8) return false;
  int q = W8 >> 3;
  int wg = ((int)blockIdx.x & 7) * q + ((int)blockIdx.x >> 3);
  if (wg >= W) return false;
  if (eSel >= 0) {
    e = eSel;
    int mb = pre[eSel + 1] - pre[eSel];
    nx = wg / mb; m0 = (wg % mb) << 8;
  } else {
    e = 0;
#pragma unroll
    for (int i = 1; i < E_NUM; ++i) if (wg >= pre[i] * nxb) e = i;
    int local = wg - pre[e] * nxb;
    int mb = pre[e + 1] - pre[e];
    nx = local / mb; m0 = (local % mb) << 8;
  }
  return true;
}

#define GEMM_CORE(AKSTRIDE, NT, STGJ)                                          \
  int tid = threadIdx.x;                                                       \
  int lane = tid & 63;                                                         \
  int wid = tid >> 6;                                                          \
  int wm = wid >> 1, wn = wid & 1;                                             \
  int lrow = lane & 15, lhi = lane >> 4;                                       \
  /* read offsets (bytes within buffer) */                                     \
  int aoff[4][2], boff[4][2];                                                  \
  _Pragma("unroll")                                                            \
  for (int m = 0; m < 4; ++m) {                                                \
    int row = wm * 64 + m * 16 + lrow;                                         \
    _Pragma("unroll")                                                          \
    for (int kk = 0; kk < 2; ++kk) {                                           \
      int s = kk * 4 + lhi;                                                    \
      aoff[m][kk] = row * 128 + ((s ^ (row & 7)) << 4);                        \
    }                                                                          \
  }                                                                            \
  _Pragma("unroll")                                                            \
  for (int n = 0; n < 4; ++n) {                                                \
    int rowb = wn * 64 + n * 16 + lrow;                                        \
    _Pragma("unroll")                                                          \
    for (int kk = 0; kk < 2; ++kk) {                                           \
      int s = kk * 4 + lhi;                                                    \
      boff[n][kk] = 32768 + rowb * 128 + ((s ^ (rowb & 7)) << 4);              \
    }                                                                          \
  }                                                                            \
  f32x4 acc[4][4];                                                             \
  _Pragma("unroll")                                                            \
  for (int m = 0; m < 4; ++m)                                                  \
    _Pragma("unroll")                                                          \
    for (int n = 0; n < 4; ++n) acc[m][n] = (f32x4){0.f, 0.f, 0.f, 0.f};       \
  /* prologue: stage tile 0 and tile 1 */                                      \
  _Pragma("unroll")                                                            \
  for (int j = 0; j < 6; ++j) STGJ(j, 0, 0);                                   \
  _Pragma("unroll")                                                            \
  for (int j = 0; j < 6; ++j) STGJ(j, 1, BUFB);                                \
  asm volatile("s_waitcnt vmcnt(6)\n\ts_barrier" ::: "memory");                \
  int cb = 0, nb = 2 * BUFB;                                                   \
  _Pragma("unroll 1")                                                          \
  for (int t = 0; t < NT; ++t) {                                               \
    bf16x8 fa[4], fb[4];                                                       \
    /* ---- phase 0 (kk = 0) ---- */                                           \
    _Pragma("unroll")                                                          \
    for (int m = 0; m < 4; ++m) fa[m] = *(const bf16x8*)(lds + cb + aoff[m][0]);\
    _Pragma("unroll")                                                          \
    for (int n = 0; n < 4; ++n) fb[n] = *(const bf16x8*)(lds + cb + boff[n][0]);\
    if (t + 2 < NT) {                                                          \
      STGJ(0, t + 2, nb); STGJ(1, t + 2, nb); STGJ(2, t + 2, nb);              \
    }                                                                          \
    __builtin_amdgcn_s_barrier();                                              \
    __builtin_amdgcn_s_setprio(1);                                             \
    _Pragma("unroll")                                                          \
    for (int m = 0; m < 4; ++m)                                                \
      _Pragma("unroll")                                                        \
      for (int n = 0; n < 4; ++n)                                              \
        acc[m][n] = __builtin_amdgcn_mfma_f32_16x16x32_bf16(fa[m], fb[n], acc[m][n], 0, 0, 0); \
    __builtin_amdgcn_s_setprio(0);                                             \
    __builtin_amdgcn_s_barrier();                                              \
    /* ---- phase 1 (kk = 1) ---- */                                           \
    _Pragma("unroll")                                                          \
    for (int m = 0; m < 4; ++m) fa[m] = *(const bf16x8*)(lds + cb + aoff[m][1]);\
    _Pragma("unroll")                                                          \
    for (int n = 0; n < 4; ++n) fb[n] = *(const bf16x8*)(lds + cb + boff[n][1]);\
    if (t + 2 < NT) {                                                          \
      STGJ(3, t + 2, nb); STGJ(4, t + 2, nb); STGJ(5, t + 2, nb);              \
    }                                                                          \
    __builtin_amdgcn_s_barrier();                                              \
    __builtin_amdgcn_s_setprio(1);                                             \
    _Pragma("unroll")                                                          \
    for (int m = 0; m < 4; ++m)                                                \
      _Pragma("unroll")                                                        \
      for (int n = 0; n < 4; ++n)                                              \
        acc[m][n] = __builtin_amdgcn_mfma_f32_16x16x32_bf16(fa[m], fb[n], acc[m][n], 0, 0, 0); \
    __builtin_amdgcn_s_setprio(0);                                             \
    if (t + 1 < NT) {                                                          \
      if (t + 2 < NT)                                                          \
        asm volatile("s_waitcnt vmcnt(6)\n\ts_barrier" ::: "memory");          \
      else                                                                     \
        asm volatile("s_waitcnt vmcnt(0)\n\ts_barrier" ::: "memory");          \
      cb = (cb == 2 * BUFB) ? 0 : cb + BUFB;                                   \
      nb = (nb == 2 * BUFB) ? 0 : nb + BUFB;                                   \
    }                                                                          \
  }

// ---------------- GEMM1: h = gelu(xg @ w1 + b1) ----------------------------
__global__ __launch_bounds__(512, 2) void gemm1_kernel(
    const unsigned short* __restrict__ xbf,   // (T+1, D), row T zeroed
    const unsigned short* __restrict__ w1t,   // (F, D) per expert
    const float* __restrict__ b1,             // (E, F)
    const int* __restrict__ dispatch,         // (E, CAP)
    const int* __restrict__ pre,              // (E+1) block prefix
    unsigned short* __restrict__ h,           // (CAP, F) per expert
    int eSel, size_t wstride, size_t hstride)
{
  int e, m0, nx;
  if (!map_block(pre, NXB1, eSel, e, m0, nx)) return;
  int ez = (eSel >= 0) ? 0 : e;
  const unsigned short* w1e = w1t + (size_t)ez * wstride;
  unsigned short* he = h + (size_t)ez * hstride;
  int n0 = nx * 128;

  __shared__ __align__(16) char lds[3 * BUFB];

  // per-thread stage descriptors: 6 loads (A chunks 0,1 = j0..3; B = j4,5)
  const unsigned short* sp[6];
  int sbase[6];
  {
    int lane_ = threadIdx.x & 63, wid_ = threadIdx.x >> 6;
#pragma unroll
    for (int j = 0; j < 6; ++j) {
      int c = j >> 1;
      int seg = wid_ * 2 + (j & 1);
      int Uc = seg * 64 + lane_;
      int rl = Uc >> 3, sl = Uc & 7;
      int colblk = (sl ^ (rl & 7)) * 8;
      if (c < 2) {
        int tok = dispatch[e * CAP + m0 + c * 128 + rl];
        sp[j] = xbf + (size_t)tok * D_DIM + colblk;
      } else {
        sp[j] = w1e + (size_t)(n0 + rl) * D_DIM + colblk;
      }
      sbase[j] = c * 16384 + seg * 1024;
    }
  }
#define STG_1(J, TT, BB) __builtin_amdgcn_global_load_lds(                     \
    (gas_ptr)(sp[J] + (TT) * 64), (las_ptr)(lds + (BB) + sbase[J]), 16, 0, 0)

  GEMM_CORE(D_DIM, (D_DIM / 64), STG_1)

  // epilogue: bias + gelu + bf16 store
  int colg[4]; float bv[4];
#pragma unroll
  for (int n = 0; n < 4; ++n) {
    colg[n] = n0 + wn * 64 + n * 16 + lrow;
    bv[n] = b1[e * F_DIM + colg[n]];
  }
#pragma unroll
  for (int m = 0; m < 4; ++m) {
#pragma unroll
    for (int j = 0; j < 4; ++j) {
      int r = m0 + wm * 64 + m * 16 + lhi * 4 + j;
      unsigned short* hr = he + (size_t)r * F_DIM;
#pragma unroll
      for (int n = 0; n < 4; ++n)
        hr[colg[n]] = f2bf(gelu_f(acc[m][n][j] + bv[n]));
    }
  }
}

// ---------------- GEMM2: out[tok] += gate * (h @ w2 + b2) -------------------
__global__ __launch_bounds__(512, 2) void gemm2_kernel(
    const unsigned short* __restrict__ h,     // (CAP, F) per expert
    const unsigned short* __restrict__ w2t,   // (D, F) per expert
    const float* __restrict__ b2,             // (E, D)
    const int* __restrict__ dispatch,
    const float* __restrict__ sgate,
    const int* __restrict__ pre,
    float* __restrict__ out,                  // (T, D) fp32, zeroed
    int eSel, size_t wstride, size_t hstride)
{
  int e, m0, nx;
  if (!map_block(pre, NXB2, eSel, e, m0, nx)) return;
  int ez = (eSel >= 0) ? 0 : e;
  const unsigned short* he = h + (size_t)ez * hstride;
  const unsigned short* w2e = w2t + (size_t)ez * wstride;
  int n0 = nx * 128;

  __shared__ __align__(16) char lds[3 * BUFB];

  const unsigned short* sp[6];
  int sbase[6];
  {
    int lane_ = threadIdx.x & 63, wid_ = threadIdx.x >> 6;
#pragma unroll
    for (int j = 0; j < 6; ++j) {
      int c = j >> 1;
      int seg = wid_ * 2 + (j & 1);
      int Uc = seg * 64 + lane_;
      int rl = Uc >> 3, sl = Uc & 7;
      int colblk = (sl ^ (rl & 7)) * 8;
      if (c < 2) {
        sp[j] = he + (size_t)(m0 + c * 128 + rl) * F_DIM + colblk;
      } else {
        sp[j] = w2e + (size_t)(n0 + rl) * F_DIM + colblk;
      }
      sbase[j] = c * 16384 + seg * 1024;
    }
  }
#define STG_2(J, TT, BB) __builtin_amdgcn_global_load_lds(                     \
    (gas_ptr)(sp[J] + (TT) * 64), (las_ptr)(lds + (BB) + sbase[J]), 16, 0, 0)

  GEMM_CORE(F_DIM, (F_DIM / 64), STG_2)

  // epilogue: bias + gate + atomic scatter by token
  int colg[4]; float bv[4];
#pragma unroll
  for (int n = 0; n < 4; ++n) {
    colg[n] = n0 + wn * 64 + n * 16 + lrow;
    bv[n] = b2[e * D_DIM + colg[n]];
  }
#pragma unroll
  for (int m = 0; m < 4; ++m) {
#pragma unroll
    for (int j = 0; j < 4; ++j) {
      int r = m0 + wm * 64 + m * 16 + lhi * 4 + j;
      int tok = dispatch[e * CAP + r];
      if (tok < T_TOK) {
        float g = sgate[e * CAP + r];
        float* orow = out + (size_t)tok * D_DIM;
#pragma unroll
        for (int n = 0; n < 4; ++n)
          atomicAdd(&orow[colg[n]], g * (acc[m][n][j] + bv[n]));
      }
    }
  }
}

// ---------------- host-side launch ------------------------------------------
extern "C" void kernel_launch(void* const* d_in, const int* in_sizes, int n_in,
                              void* d_out, int out_size, void* d_ws, size_t ws_size,
                              hipStream_t stream) {
  const float* x  = (const float*)d_in[0];
  const float* wr = (const float*)d_in[1];
  const float* w1 = (const float*)d_in[2];
  const float* b1 = (const float*)d_in[3];
  const float* w2 = (const float*)d_in[4];
  const float* b2 = (const float*)d_in[5];
  float* out = (float*)d_out;

  char* ws = (char*)d_ws;
  size_t off = 0;
  auto alloc = [&](size_t bytes) -> void* {
    off = (off + 255) & ~(size_t)255;
    void* p = ws + off;
    off += bytes;
    return p;
  };
  int*   dispatch = (int*)alloc((size_t)E_NUM * CAP * 4);
  float* sgate    = (float*)alloc((size_t)E_NUM * CAP * 4);
  int*   cnt      = (int*)alloc((size_t)E_NUM * 4);
  int*   pre      = (int*)alloc((size_t)(E_NUM + 1) * 4);
  int2*  tokE     = (int2*)alloc((size_t)T_TOK * 8);
  float2* tokG    = (float2*)alloc((size_t)T_TOK * 8);
  unsigned short* xbf = (unsigned short*)alloc((size_t)(T_TOK + 1) * D_DIM * 2);

  const size_t wsz = (size_t)D_DIM * F_DIM * 2;  // one expert weight, bf16
  const size_t hsz = (size_t)CAP * F_DIM * 2;    // one expert h, bf16
  size_t remain = ws_size > off ? ws_size - off : 0;
  bool tierA = remain >= (size_t)E_NUM * (2 * wsz + hsz) + (size_t)(1 << 16);

  hipMemsetAsync(out, 0, (size_t)T_TOK * D_DIM * 4, stream);
  hipMemsetAsync(xbf + (size_t)T_TOK * D_DIM, 0, D_DIM * 2, stream);
  route_kernel<<<T_TOK / 4, 256, 0, stream>>>(x, wr, xbf, tokE, tokG);
  scan_kernel<<<E_NUM, 256, 0, stream>>>(tokE, tokG, dispatch, sgate, cnt);
  plan_kernel<<<1, 64, 0, stream>>>(cnt, pre);

  if (tierA) {
    unsigned short* w1t = (unsigned short*)alloc((size_t)E_NUM * wsz);
    unsigned short* w2t = (unsigned short*)alloc((size_t)E_NUM * wsz);
    unsigned short* hb  = (unsigned short*)alloc((size_t)E_NUM * hsz);
    transpose_kernel<<<dim3(F_DIM / 64, D_DIM / 64, E_NUM), 256, 0, stream>>>(w1, w1t, D_DIM, F_DIM);
    transpose_kernel<<<dim3(D_DIM / 64, F_DIM / 64, E_NUM), 256, 0, stream>>>(w2, w2t, F_DIM, D_DIM);
    gemm1_kernel<<<dim3(NWMAX * NXB1), 512, 0, stream>>>(
        xbf, w1t, b1, dispatch, pre, hb, -1, wsz / 2, hsz / 2);
    gemm2_kernel<<<dim3(NWMAX * NXB2), 512, 0, stream>>>(
        hb, w2t, b2, dispatch, sgate, pre, out, -1, wsz / 2, hsz / 2);
  } else {
    unsigned short* w1t = (unsigned short*)alloc(wsz);
    unsigned short* w2t = (unsigned short*)alloc(wsz);
    unsigned short* hb  = (unsigned short*)alloc(hsz);
    for (int e = 0; e < E_NUM; ++e) {
      transpose_kernel<<<dim3(F_DIM / 64, D_DIM / 64, 1), 256, 0, stream>>>(
          w1 + (size_t)e * D_DIM * F_DIM, w1t, D_DIM, F_DIM);
      gemm1_kernel<<<dim3((CAP / 256) * NXB1), 512, 0, stream>>>(
          xbf, w1t, b1, dispatch, pre, hb, e, 0, 0);
      transpose_kernel<<<dim3(D_DIM / 64, F_DIM / 64, 1), 256, 0, stream>>>(
          w2 + (size_t)e * D_DIM * F_DIM, w2t, F_DIM, D_DIM);
      gemm2_kernel<<<dim3((CAP / 256) * NXB2), 512, 0, stream>>>(
          hb, w2t, b2, dispatch, sgate, pre, out, e, 0, 0);
    }
  }
}